// Round 14
// baseline (26.132 us; speedup 1.0000x reference)
//
#include <hip/hip_runtime.h>

// LDDMM variational evolve: N-body Gaussian kernel sums, N=8192, D=3, fp32.
// dmom_i = (1/SIG2) * sum_j K_ij * <mom_i,mom_j> * (pos_i - pos_j)
// dpos_i = sum_j K_ij * mom_j
// K_ij = exp(-||xi-xj||^2/(2*SIG2)), SIG2=0.01 -> exp2(-72.1348*d2)
//
// Cell list: K < 4e-6 for d2 > 0.25; dropped-pair error ~1e-2 << thr 2.36.
// Ladder: R9 27-cell 36.5; R12 z-merged columns 29.9; R13 z-slab clip +
// 3 dispatches 24.9. R14: k_main is L2-BW bound (~270 MB of j-records) ->
// (1) 2 consecutive sorted points per wave: every 32B load feeds 2 evals
// (traffic halves; union column ranges, no fallback path);
// (2) per-column z-clip: window = zi +- sqrt(0.25 - minxy^2) where minxy =
// xy-distance to column footprint; empty -> column skipped. Keeps ALL pairs
// with d2 <= 0.25 (same error budget), cuts ~25% of pairs+loads.
// R7 NaN lesson: ci stays inside the exponent (arg <= 0 always).
// exp = __builtin_amdgcn_exp2f (plain exp2f -> OCML fixup; R2 measured).

#define NPTS  8192
#define NCXY  16
#define NCZ   32
#define NCELL (NCXY * NCXY * NCZ)   // 8192
#define ORIGIN    (-4.0f)
#define EDGE      0.5f
#define INV_EDGE  2.0f              // xy edge 0.5
#define INV_EDGEZ 4.0f              // z slab 0.25
#define RCUT      0.5f
#define RCUT2     0.25f

#define A_DOT 144.269504088896f     // 2*50*log2(e)
#define A_R   (-72.134752044448f)   // -50*log2(e)
#define INV_SIG2 100.0f

#define EXP2(x) __builtin_amdgcn_exp2f(x)

__device__ __forceinline__ int clampi(int c, int hi) { return min(max(c, 0), hi); }

__device__ __forceinline__ int cell_of(float x, float y, float z) {
    const int cx = clampi((int)floorf((x - ORIGIN) * INV_EDGE),  NCXY - 1);
    const int cy = clampi((int)floorf((y - ORIGIN) * INV_EDGE),  NCXY - 1);
    const int cz = clampi((int)floorf((z - ORIGIN) * INV_EDGEZ), NCZ  - 1);
    return (cx * NCXY + cy) * NCZ + cz;
}

// ---------------- prep 1: count (LDS hist) + scan, one block ----------------
__global__ __launch_bounds__(1024)
void k_countscan(const float* __restrict__ pos,
                 int* __restrict__ start, int* __restrict__ cur)
{
    __shared__ int cnt[NCELL];      // 32 KB
    __shared__ int wtot[16];
    __shared__ int wexcl[16];
    const int t = threadIdx.x;
    const int lane = t & 63;
    const int wid = t >> 6;

    #pragma unroll
    for (int k = 0; k < NCELL / 1024; ++k) cnt[t + k * 1024] = 0;
    __syncthreads();

    #pragma unroll
    for (int k = 0; k < NPTS / 1024; ++k) {
        const int i = t + k * 1024;
        atomicAdd(&cnt[cell_of(pos[3*i+0], pos[3*i+1], pos[3*i+2])], 1);
    }
    __syncthreads();

    // scan 8192 bins: thread t owns cells 8t..8t+7
    int pre[8];
    int s = 0;
    #pragma unroll
    for (int k = 0; k < 8; ++k) { pre[k] = s; s += cnt[8*t + k]; }
    int p = s;
    #pragma unroll
    for (int off = 1; off < 64; off <<= 1) {
        const int v = __shfl_up(p, off);
        if (lane >= off) p += v;
    }
    if (lane == 63) wtot[wid] = p;
    __syncthreads();
    if (t < 16) {
        const int w = wtot[t];
        int q = w;
        #pragma unroll
        for (int off = 1; off < 16; off <<= 1) {
            const int v = __shfl_up(q, off);
            if (t >= off) q += v;
        }
        wexcl[t] = q - w;
    }
    __syncthreads();
    const int base = wexcl[wid] + (p - s);
    #pragma unroll
    for (int k = 0; k < 8; ++k) {
        const int v = base + pre[k];
        start[8*t + k] = v;
        cur[8*t + k] = v;
    }
    if (t == 0) start[NCELL] = NPTS;
}

// ---------------- prep 2: scatter (parallel, atomic cursor ranks) ----------------
__global__ __launch_bounds__(256)
void k_scatter(const float* __restrict__ mom, const float* __restrict__ pos,
               int* __restrict__ cur,
               float* __restrict__ pmP, float* __restrict__ pmM,
               int* __restrict__ inv)
{
    const int i = blockIdx.x * 256 + threadIdx.x;
    const float x = pos[3*i+0], y = pos[3*i+1], z = pos[3*i+2];
    const int dst = atomicAdd(&cur[cell_of(x, y, z)], 1);
    const float r2 = x*x + y*y + z*z;
    reinterpret_cast<float4*>(pmP)[dst] = make_float4(A_DOT*x, A_DOT*y, A_DOT*z, A_R*r2);
    reinterpret_cast<float4*>(pmM)[dst] = make_float4(mom[3*i+0], mom[3*i+1], mom[3*i+2], 0.0f);
    inv[dst] = i;
}

// ---------------- main: one wave per 2 sorted points, per-column z-clip ----------------
__device__ __forceinline__ void eval_one(
    const float4 P, const float4 M,
    const float xi, const float yi, const float zi, const float ci,
    const float pxi, const float pyi, const float pzi,
    float& S, float& SPx, float& SPy, float& SPz,
    float& apx, float& apy, float& apz)
{
    // arg = ci + A_DOT*<xi,xj> + A_R*rj2 = -72.13*d2 <= 0 (no overflow)
    float arg = __builtin_fmaf(zi, P.z, ci + P.w);
    arg = __builtin_fmaf(yi, P.y, arg);
    arg = __builtin_fmaf(xi, P.x, arg);
    const float K = EXP2(arg);
    const float C = __builtin_fmaf(pzi, M.z, __builtin_fmaf(pyi, M.y, pxi * M.x));
    const float s = K * C;
    S += s;
    SPx = __builtin_fmaf(s, P.x, SPx);
    SPy = __builtin_fmaf(s, P.y, SPy);
    SPz = __builtin_fmaf(s, P.z, SPz);
    apx = __builtin_fmaf(K, M.x, apx);
    apy = __builtin_fmaf(K, M.y, apy);
    apz = __builtin_fmaf(K, M.z, apz);
}

// z-window [z0,z1] (slab indices) for point (x,y,z) vs column footprint
// [X0,X0+EDGE]x[Y0,Y0+EDGE]; empty -> z0 > z1.
__device__ __forceinline__ void zwin(float x, float y, float z,
                                     float X0, float Y0, int& z0, int& z1)
{
    const float dx = fmaxf(fmaxf(X0 - x, x - (X0 + EDGE)), 0.0f);
    const float dy = fmaxf(fmaxf(Y0 - y, y - (Y0 + EDGE)), 0.0f);
    const float m2 = dx * dx + dy * dy;
    if (m2 <= RCUT2) {
        const float zr = __builtin_sqrtf(RCUT2 - m2);
        z0 = clampi((int)floorf((z - zr - ORIGIN) * INV_EDGEZ), NCZ - 1);
        z1 = clampi((int)floorf((z + zr - ORIGIN) * INV_EDGEZ), NCZ - 1);
    } else {
        z0 = 1; z1 = 0;   // empty
    }
}

__global__ __launch_bounds__(256)
void k_main(const float* __restrict__ mom, const float* __restrict__ pos,
            const float* __restrict__ pmP, const float* __restrict__ pmM,
            const int* __restrict__ inv, const int* __restrict__ start,
            float* __restrict__ out)
{
    const int w    = (blockIdx.x * 256 + threadIdx.x) >> 6;   // 0..4095
    const int lane = threadIdx.x & 63;

    const int oiA = inv[2*w], oiB = inv[2*w + 1];             // wave-uniform
    const float xA = pos[3*oiA+0], yA = pos[3*oiA+1], zA = pos[3*oiA+2];
    const float pxA = mom[3*oiA+0], pyA = mom[3*oiA+1], pzA = mom[3*oiA+2];
    const float xB = pos[3*oiB+0], yB = pos[3*oiB+1], zB = pos[3*oiB+2];
    const float pxB = mom[3*oiB+0], pyB = mom[3*oiB+1], pzB = mom[3*oiB+2];
    const float cA = A_R * (xA*xA + yA*yA + zA*zA);
    const float cB = A_R * (xB*xB + yB*yB + zB*zB);

    const int cxA = clampi((int)floorf((xA - ORIGIN) * INV_EDGE), NCXY - 1);
    const int cyA = clampi((int)floorf((yA - ORIGIN) * INV_EDGE), NCXY - 1);
    const int cxB = clampi((int)floorf((xB - ORIGIN) * INV_EDGE), NCXY - 1);
    const int cyB = clampi((int)floorf((yB - ORIGIN) * INV_EDGE), NCXY - 1);
    const int x0 = max(min(cxA, cxB) - 1, 0), x1 = min(max(cxA, cxB) + 1, NCXY - 1);
    const int y0 = max(min(cyA, cyB) - 1, 0), y1 = min(max(cyA, cyB) + 1, NCXY - 1);
    const int wy = y1 - y0 + 1;
    const int ncol = (x1 - x0 + 1) * wy;                      // 4..12

    // Lanes 0..ncol-1: union per-column z-clipped range.
    int st_l = 0, en_l = 0;
    if (lane < ncol) {
        const int nx = x0 + lane / wy;
        const int ny = y0 + lane % wy;
        const float X0 = ORIGIN + nx * EDGE;
        const float Y0 = ORIGIN + ny * EDGE;
        int a0, a1, b0, b1;
        zwin(xA, yA, zA, X0, Y0, a0, a1);
        zwin(xB, yB, zB, X0, Y0, b0, b1);
        // union (empty windows excluded)
        int zlo = NCZ, zhi = -1;
        if (a0 <= a1) { zlo = a0; zhi = a1; }
        if (b0 <= b1) { zlo = min(zlo, b0); zhi = max(zhi, b1); }
        if (zlo <= zhi) {
            const int base = (nx * NCXY + ny) * NCZ;
            st_l = start[base + zlo];
            en_l = start[base + zhi + 1];
        }
    }

    float SA=0.f, SPAx=0.f, SPAy=0.f, SPAz=0.f, apAx=0.f, apAy=0.f, apAz=0.f;
    float SB=0.f, SPBx=0.f, SPBy=0.f, SPBz=0.f, apBx=0.f, apBy=0.f, apBz=0.f;

    const float4* __restrict__ pmPv = reinterpret_cast<const float4*>(pmP);
    const float4* __restrict__ pmMv = reinterpret_cast<const float4*>(pmM);

    for (int p = 0; p < ncol; ++p) {
        const int st = __shfl(st_l, p);
        const int en = __shfl(en_l, p);
        for (int j = st + lane; j < en; j += 64) {
            const float4 P = pmPv[j];                         // coalesced, shared
            const float4 M = pmMv[j];
            eval_one(P, M, xA, yA, zA, cA, pxA, pyA, pzA,
                     SA, SPAx, SPAy, SPAz, apAx, apAy, apAz);
            eval_one(P, M, xB, yB, zB, cB, pxB, pyB, pzB,
                     SB, SPBx, SPBy, SPBz, apBx, apBy, apBz);
        }
    }

    // 64-lane butterfly reduce of all 14 accumulators.
    #pragma unroll
    for (int off = 1; off < 64; off <<= 1) {
        SA   += __shfl_xor(SA,   off);
        SPAx += __shfl_xor(SPAx, off);
        SPAy += __shfl_xor(SPAy, off);
        SPAz += __shfl_xor(SPAz, off);
        apAx += __shfl_xor(apAx, off);
        apAy += __shfl_xor(apAy, off);
        apAz += __shfl_xor(apAz, off);
        SB   += __shfl_xor(SB,   off);
        SPBx += __shfl_xor(SPBx, off);
        SPBy += __shfl_xor(SPBy, off);
        SPBz += __shfl_xor(SPBz, off);
        apBx += __shfl_xor(apBx, off);
        apBy += __shfl_xor(apBy, off);
        apBz += __shfl_xor(apBz, off);
    }

    const float us = INV_SIG2 / A_DOT;
    if (lane == 0) {
        out[3*oiA+0] = INV_SIG2 * xA * SA - us * SPAx;
        out[3*oiA+1] = INV_SIG2 * yA * SA - us * SPAy;
        out[3*oiA+2] = INV_SIG2 * zA * SA - us * SPAz;
        out[3*NPTS + 3*oiA+0] = apAx;
        out[3*NPTS + 3*oiA+1] = apAy;
        out[3*NPTS + 3*oiA+2] = apAz;
    } else if (lane == 1) {
        out[3*oiB+0] = INV_SIG2 * xB * SB - us * SPBx;
        out[3*oiB+1] = INV_SIG2 * yB * SB - us * SPBy;
        out[3*oiB+2] = INV_SIG2 * zB * SB - us * SPBz;
        out[3*NPTS + 3*oiB+0] = apBx;
        out[3*NPTS + 3*oiB+1] = apBy;
        out[3*NPTS + 3*oiB+2] = apBz;
    }
}

extern "C" void kernel_launch(void* const* d_in, const int* in_sizes, int n_in,
                              void* d_out, int out_size, void* d_ws, size_t ws_size,
                              hipStream_t stream)
{
    const float* mom = (const float*)d_in[0];
    const float* pos = (const float*)d_in[1];
    float* out = (float*)d_out;

    // ws layout: pmP (4*NPTS f), pmM (4*NPTS f), inv (NPTS i),
    //            start (NCELL+1 i), cur (NCELL i)  -> ~355 KB
    float* pmP  = (float*)d_ws;
    float* pmM  = pmP + (size_t)4 * NPTS;
    int* inv    = (int*)(pmM + (size_t)4 * NPTS);
    int* start  = inv + NPTS;
    int* cur    = start + NCELL + 1;

    k_countscan<<<1, 1024, 0, stream>>>(pos, start, cur);
    k_scatter<<<NPTS / 256, 256, 0, stream>>>(mom, pos, cur, pmP, pmM, inv);
    k_main<<<(NPTS / 2 * 64) / 256, 256, 0, stream>>>(mom, pos, pmP, pmM, inv, start, out);
}

// Round 15
// 24.415 us; speedup vs baseline: 1.0703x; 1.0703x over previous
//
#include <hip/hip_runtime.h>

// LDDMM variational evolve: N-body Gaussian kernel sums, N=8192, D=3, fp32.
// dmom_i = (1/SIG2) * sum_j K_ij * <mom_i,mom_j> * (pos_i - pos_j)
// dpos_i = sum_j K_ij * mom_j
// K_ij = exp(-||xi-xj||^2/(2*SIG2)), SIG2=0.01 -> exp2(-72.1348*d2)
//
// Cell list: K < 4e-6 for d2 > 0.25; dropped-pair error ~1e-2 << thr 2.36.
// Ladder: R9 27-cell 36.5; R12 z-merge 29.9; R13 z-slab + 3 dispatches 24.9;
// R14 pairing+zclip REGRESSED 26.1 -> main is ISSUE/LATENCY-bound, not L2-BW
// (halved traffic, time up). R15 deconfounds: R13 single-point structure +
// per-column z-clip only (window = zi +- sqrt(0.25-m^2), m = xy-dist to
// column footprint; keeps ALL d2<=0.25 pairs) + fixed 3x3 column enum
// (no runtime int div; constant-trip unrolled column loop, readlane bounds).
// R7 NaN lesson: ci stays inside the exponent (arg <= 0 always).
// exp = __builtin_amdgcn_exp2f (plain exp2f -> OCML fixup; R2 measured).

#define NPTS  8192
#define NCXY  16
#define NCZ   32
#define NCELL (NCXY * NCXY * NCZ)   // 8192
#define ORIGIN    (-4.0f)
#define EDGE      0.5f
#define INV_EDGE  2.0f              // xy edge 0.5
#define INV_EDGEZ 4.0f              // z slab 0.25
#define RCUT2     0.25f

#define A_DOT 144.269504088896f     // 2*50*log2(e)
#define A_R   (-72.134752044448f)   // -50*log2(e)
#define INV_SIG2 100.0f

#define EXP2(x) __builtin_amdgcn_exp2f(x)

__device__ __forceinline__ int clampi(int c, int hi) { return min(max(c, 0), hi); }

__device__ __forceinline__ int cell_of(float x, float y, float z) {
    const int cx = clampi((int)floorf((x - ORIGIN) * INV_EDGE),  NCXY - 1);
    const int cy = clampi((int)floorf((y - ORIGIN) * INV_EDGE),  NCXY - 1);
    const int cz = clampi((int)floorf((z - ORIGIN) * INV_EDGEZ), NCZ  - 1);
    return (cx * NCXY + cy) * NCZ + cz;
}

// ---------------- prep 1: count (LDS hist) + scan, one block ----------------
__global__ __launch_bounds__(1024)
void k_countscan(const float* __restrict__ pos,
                 int* __restrict__ start, int* __restrict__ cur)
{
    __shared__ int cnt[NCELL];      // 32 KB
    __shared__ int wtot[16];
    __shared__ int wexcl[16];
    const int t = threadIdx.x;
    const int lane = t & 63;
    const int wid = t >> 6;

    #pragma unroll
    for (int k = 0; k < NCELL / 1024; ++k) cnt[t + k * 1024] = 0;
    __syncthreads();

    #pragma unroll
    for (int k = 0; k < NPTS / 1024; ++k) {
        const int i = t + k * 1024;
        atomicAdd(&cnt[cell_of(pos[3*i+0], pos[3*i+1], pos[3*i+2])], 1);
    }
    __syncthreads();

    // scan 8192 bins: thread t owns cells 8t..8t+7
    int pre[8];
    int s = 0;
    #pragma unroll
    for (int k = 0; k < 8; ++k) { pre[k] = s; s += cnt[8*t + k]; }
    int p = s;
    #pragma unroll
    for (int off = 1; off < 64; off <<= 1) {
        const int v = __shfl_up(p, off);
        if (lane >= off) p += v;
    }
    if (lane == 63) wtot[wid] = p;
    __syncthreads();
    if (t < 16) {
        const int w = wtot[t];
        int q = w;
        #pragma unroll
        for (int off = 1; off < 16; off <<= 1) {
            const int v = __shfl_up(q, off);
            if (t >= off) q += v;
        }
        wexcl[t] = q - w;
    }
    __syncthreads();
    const int base = wexcl[wid] + (p - s);
    #pragma unroll
    for (int k = 0; k < 8; ++k) {
        const int v = base + pre[k];
        start[8*t + k] = v;
        cur[8*t + k] = v;
    }
    if (t == 0) start[NCELL] = NPTS;
}

// ---------------- prep 2: scatter (parallel, atomic cursor ranks) ----------------
__global__ __launch_bounds__(256)
void k_scatter(const float* __restrict__ mom, const float* __restrict__ pos,
               int* __restrict__ cur,
               float* __restrict__ pmP, float* __restrict__ pmM,
               int* __restrict__ inv)
{
    const int i = blockIdx.x * 256 + threadIdx.x;
    const float x = pos[3*i+0], y = pos[3*i+1], z = pos[3*i+2];
    const int dst = atomicAdd(&cur[cell_of(x, y, z)], 1);
    const float r2 = x*x + y*y + z*z;
    reinterpret_cast<float4*>(pmP)[dst] = make_float4(A_DOT*x, A_DOT*y, A_DOT*z, A_R*r2);
    reinterpret_cast<float4*>(pmM)[dst] = make_float4(mom[3*i+0], mom[3*i+1], mom[3*i+2], 0.0f);
    inv[dst] = i;
}

// ---------------- main: one wave per point, 3x3 columns, per-column z-clip ----
__global__ __launch_bounds__(256)
void k_main(const float* __restrict__ mom, const float* __restrict__ pos,
            const float* __restrict__ pmP, const float* __restrict__ pmM,
            const int* __restrict__ inv, const int* __restrict__ start,
            float* __restrict__ out)
{
    const int wid  = (blockIdx.x * 256 + threadIdx.x) >> 6;   // 0..8191
    const int lane = threadIdx.x & 63;

    const int oi = inv[wid];                                  // wave-uniform
    const float xi = pos[3*oi+0], yi = pos[3*oi+1], zi = pos[3*oi+2];
    const float pxi = mom[3*oi+0], pyi = mom[3*oi+1], pzi = mom[3*oi+2];
    const float ci  = A_R * (xi*xi + yi*yi + zi*zi);

    const int cx = clampi((int)floorf((xi - ORIGIN) * INV_EDGE), NCXY - 1);
    const int cy = clampi((int)floorf((yi - ORIGIN) * INV_EDGE), NCXY - 1);

    // Lanes 0..8: fixed 3x3 columns; out-of-domain or xy-pruned -> empty.
    int st_l = 0, en_l = 0;
    if (lane < 9) {
        const int nx = cx + (lane / 3) - 1;   // div by const: cheap
        const int ny = cy + (lane % 3) - 1;
        if (nx >= 0 && nx < NCXY && ny >= 0 && ny < NCXY) {
            const float X0 = ORIGIN + nx * EDGE;
            const float Y0 = ORIGIN + ny * EDGE;
            const float dx = fmaxf(fmaxf(X0 - xi, xi - (X0 + EDGE)), 0.0f);
            const float dy = fmaxf(fmaxf(Y0 - yi, yi - (Y0 + EDGE)), 0.0f);
            const float m2 = dx * dx + dy * dy;
            if (m2 <= RCUT2) {
                const float zr = __builtin_sqrtf(RCUT2 - m2);
                const int z0 = clampi((int)floorf((zi - zr - ORIGIN) * INV_EDGEZ), NCZ - 1);
                const int z1 = clampi((int)floorf((zi + zr - ORIGIN) * INV_EDGEZ), NCZ - 1);
                const int base = (nx * NCXY + ny) * NCZ;
                st_l = start[base + z0];
                en_l = start[base + z1 + 1];
            }
        }
    }

    float S = 0.f, SPx = 0.f, SPy = 0.f, SPz = 0.f;
    float apx = 0.f, apy = 0.f, apz = 0.f;

    const float4* __restrict__ pmPv = reinterpret_cast<const float4*>(pmP);
    const float4* __restrict__ pmMv = reinterpret_cast<const float4*>(pmM);

    #pragma unroll
    for (int p = 0; p < 9; ++p) {
        const int st = __shfl(st_l, p);       // constant lane -> readlane (SGPR)
        const int en = __shfl(en_l, p);
        for (int j = st + lane; j < en; j += 64) {
            const float4 P = pmPv[j];         // coalesced
            const float4 M = pmMv[j];
            // arg = ci + A_DOT*<xi,xj> + A_R*rj2 = -72.13*d2 <= 0 (no overflow)
            float arg = __builtin_fmaf(zi, P.z, ci + P.w);
            arg = __builtin_fmaf(yi, P.y, arg);
            arg = __builtin_fmaf(xi, P.x, arg);
            const float K = EXP2(arg);
            const float C = __builtin_fmaf(pzi, M.z,
                              __builtin_fmaf(pyi, M.y, pxi * M.x));
            const float s = K * C;
            S += s;
            SPx = __builtin_fmaf(s, P.x, SPx);
            SPy = __builtin_fmaf(s, P.y, SPy);
            SPz = __builtin_fmaf(s, P.z, SPz);
            apx = __builtin_fmaf(K, M.x, apx);
            apy = __builtin_fmaf(K, M.y, apy);
            apz = __builtin_fmaf(K, M.z, apz);
        }
    }

    // 64-lane butterfly reduce of the 7 accumulators.
    #pragma unroll
    for (int off = 1; off < 64; off <<= 1) {
        S   += __shfl_xor(S,   off);
        SPx += __shfl_xor(SPx, off);
        SPy += __shfl_xor(SPy, off);
        SPz += __shfl_xor(SPz, off);
        apx += __shfl_xor(apx, off);
        apy += __shfl_xor(apy, off);
        apz += __shfl_xor(apz, off);
    }

    if (lane == 0) {
        const float us = INV_SIG2 / A_DOT;
        out[3*oi+0] = INV_SIG2 * xi * S - us * SPx;
        out[3*oi+1] = INV_SIG2 * yi * S - us * SPy;
        out[3*oi+2] = INV_SIG2 * zi * S - us * SPz;
        out[3*NPTS + 3*oi+0] = apx;
        out[3*NPTS + 3*oi+1] = apy;
        out[3*NPTS + 3*oi+2] = apz;
    }
}

extern "C" void kernel_launch(void* const* d_in, const int* in_sizes, int n_in,
                              void* d_out, int out_size, void* d_ws, size_t ws_size,
                              hipStream_t stream)
{
    const float* mom = (const float*)d_in[0];
    const float* pos = (const float*)d_in[1];
    float* out = (float*)d_out;

    // ws layout: pmP (4*NPTS f), pmM (4*NPTS f), inv (NPTS i),
    //            start (NCELL+1 i), cur (NCELL i)  -> ~355 KB
    float* pmP  = (float*)d_ws;
    float* pmM  = pmP + (size_t)4 * NPTS;
    int* inv    = (int*)(pmM + (size_t)4 * NPTS);
    int* start  = inv + NPTS;
    int* cur    = start + NCELL + 1;

    k_countscan<<<1, 1024, 0, stream>>>(pos, start, cur);
    k_scatter<<<NPTS / 256, 256, 0, stream>>>(mom, pos, cur, pmP, pmM, inv);
    k_main<<<(NPTS * 64) / 256, 256, 0, stream>>>(mom, pos, pmP, pmM, inv, start, out);
}